// Round 10
// baseline (231.293 us; speedup 1.0000x reference)
//
#include <hip/hip_runtime.h>
#include <hip/hip_bf16.h>
#include <math.h>

#define N_NODES 50000
#define N_EDGES 800000
#define DIM 96
#define HEADS 4
#define HEAD_DIM 24
#define SLOPE 0.2f
#define LN_EPS 1e-5f

#define GT 384        // 6 waves; 12 feat-groups (8 feats) x 32 node-groups (2 nodes)
#define TNODES 64     // nodes per tile
#define XPAD 100      // x/g tile row stride (400B: 16B-aligned)
#define NTILES ((N_NODES + TNODES - 1) / TNODES)   // 782

#define SCAN_BLK 512
#define SCAN_NB ((N_NODES + SCAN_BLK - 1) / SCAN_BLK)   // 98

__device__ __forceinline__ unsigned short f2bf(float f) {
    unsigned u = __float_as_uint(f);
    u += 0x7FFFu + ((u >> 16) & 1u);          // round-to-nearest-even
    return (unsigned short)(u >> 16);
}
__device__ __forceinline__ float bf2f(unsigned short v) {
    return __uint_as_float(((unsigned)v) << 16);
}
__device__ __forceinline__ unsigned pack2bf(float a, float b) {
    return (unsigned)f2bf(a) | ((unsigned)f2bf(b) << 16);
}

// ---------------------------------------------------------------------------
// Prep: zero counts + transpose PW (PWT[k][f] = PW[f][k]) in one dispatch.
// ---------------------------------------------------------------------------
__global__ void k_prep(const float* __restrict__ PW, float* __restrict__ pwt,
                       int* __restrict__ counts)
{
    const int i = blockIdx.x * 256 + threadIdx.x;
    if (i < N_NODES) counts[i] = 0;
    if (i < DIM * DIM) pwt[i] = PW[(i % DIM) * DIM + i / DIM];
}

// ---------------------------------------------------------------------------
// Kernel A: h = x @ W, 2-node x 8-feat register tile, float4 LDS reads.
// h stored bf16; attention dots from f32 h-tile staged back to LDS.
// ---------------------------------------------------------------------------
__global__ __launch_bounds__(GT) void k_transform(
    const float* __restrict__ x, const float* __restrict__ W,
    const float* __restrict__ attS, const float* __restrict__ attD,
    unsigned short* __restrict__ hb, float* __restrict__ asrc,
    float* __restrict__ adst)
{
    __shared__ float Wl[DIM][DIM];        // [k][f] 36.9 KB
    __shared__ float xl[TNODES][XPAD];    // 25.6 KB (reused as h-tile)
    __shared__ float attl[2][DIM];
    const int tid = threadIdx.x;
    for (int i4 = tid; i4 < DIM * (DIM / 4); i4 += GT) {     // float4 staging
        const int k = i4 / 24, q = i4 % 24;
        *(float4*)&Wl[k][q * 4] = *(const float4*)&W[k * DIM + q * 4];
    }
    if (tid < DIM) { attl[0][tid] = attS[tid]; attl[1][tid] = attD[tid]; }
    const int tf = tid % 12, tn = tid / 12;   // 12 feat-groups x 32 node-groups
    const int f0 = tf * 8, n0 = tn * 2;

    for (int tile = blockIdx.x; tile < NTILES; tile += gridDim.x) {
        const int base = tile * TNODES;
        __syncthreads();   // Wl ready (iter 0); xl consumers done (iter>0)
        for (int i4 = tid; i4 < TNODES * 24; i4 += GT) {
            const int n = i4 / 24, q = i4 % 24, gn = base + n;
            *(float4*)&xl[n][q * 4] = (gn < N_NODES)
                ? *(const float4*)&x[(size_t)gn * DIM + q * 4]
                : make_float4(0.f, 0.f, 0.f, 0.f);
        }
        __syncthreads();
        float acc[2][8] = {};
        for (int k = 0; k < DIM; k += 4) {
            float4 xq[2], wa[4], wb[4];
            #pragma unroll
            for (int a = 0; a < 2; ++a) xq[a] = *(const float4*)&xl[n0 + a][k];
            #pragma unroll
            for (int j = 0; j < 4; ++j) {
                wa[j] = *(const float4*)&Wl[k + j][f0];
                wb[j] = *(const float4*)&Wl[k + j][f0 + 4];
            }
            #pragma unroll
            for (int a = 0; a < 2; ++a) {
                const float x0 = xq[a].x, x1 = xq[a].y, x2 = xq[a].z, x3 = xq[a].w;
                acc[a][0] += x0*wa[0].x + x1*wa[1].x + x2*wa[2].x + x3*wa[3].x;
                acc[a][1] += x0*wa[0].y + x1*wa[1].y + x2*wa[2].y + x3*wa[3].y;
                acc[a][2] += x0*wa[0].z + x1*wa[1].z + x2*wa[2].z + x3*wa[3].z;
                acc[a][3] += x0*wa[0].w + x1*wa[1].w + x2*wa[2].w + x3*wa[3].w;
                acc[a][4] += x0*wb[0].x + x1*wb[1].x + x2*wb[2].x + x3*wb[3].x;
                acc[a][5] += x0*wb[0].y + x1*wb[1].y + x2*wb[2].y + x3*wb[3].y;
                acc[a][6] += x0*wb[0].z + x1*wb[1].z + x2*wb[2].z + x3*wb[3].z;
                acc[a][7] += x0*wb[0].w + x1*wb[1].w + x2*wb[2].w + x3*wb[3].w;
            }
        }
        #pragma unroll
        for (int a = 0; a < 2; ++a) {
            const int gn = base + n0 + a;
            if (gn < N_NODES) {
                uint4 hv;
                hv.x = pack2bf(acc[a][0], acc[a][1]);
                hv.y = pack2bf(acc[a][2], acc[a][3]);
                hv.z = pack2bf(acc[a][4], acc[a][5]);
                hv.w = pack2bf(acc[a][6], acc[a][7]);
                *(uint4*)&hb[(size_t)gn * DIM + f0] = hv;   // 8 bf16 = 16B
            }
        }
        __syncthreads();   // all xl reads done -> reuse as f32 h-tile
        #pragma unroll
        for (int a = 0; a < 2; ++a) {
            *(float4*)&xl[n0 + a][f0]     = make_float4(acc[a][0], acc[a][1], acc[a][2], acc[a][3]);
            *(float4*)&xl[n0 + a][f0 + 4] = make_float4(acc[a][4], acc[a][5], acc[a][6], acc[a][7]);
        }
        __syncthreads();
        for (int i = tid; i < TNODES * HEADS; i += GT) {     // (node, head) dots
            const int l = i >> 2, hd = i & 3, gn = base + l;
            if (gn < N_NODES) {
                float s = 0.f, dd = 0.f;
                #pragma unroll
                for (int kk = 0; kk < HEAD_DIM; ++kk) {
                    const float hv = xl[l][hd * HEAD_DIM + kk];
                    s  += hv * attl[0][hd * HEAD_DIM + kk];
                    dd += hv * attl[1][hd * HEAD_DIM + kk];
                }
                asrc[gn * HEADS + hd] = s;
                adst[gn * HEADS + hd] = dd;
            }
        }
    }
}

// ---------------------------------------------------------------------------
// CSR build: histogram -> partial sums -> (bsum-scan fused) final scan
// ---------------------------------------------------------------------------
__global__ void k_hist(const int* __restrict__ ei, int* __restrict__ counts)
{
    const int e = blockIdx.x * 256 + threadIdx.x;
    if (e >= N_EDGES) return;
    const int d = ei[N_EDGES + e];
    if ((unsigned)d < N_NODES) atomicAdd(&counts[d], 1);
}

__global__ __launch_bounds__(SCAN_BLK) void k_scan_partial(
    const int* __restrict__ counts, int* __restrict__ bsum)
{
    __shared__ int red[SCAN_BLK];
    const int t = threadIdx.x;
    const int i = blockIdx.x * SCAN_BLK + t;
    red[t] = (i < N_NODES) ? counts[i] : 0;
    __syncthreads();
    #pragma unroll
    for (int off = SCAN_BLK / 2; off > 0; off >>= 1) {
        if (t < off) red[t] += red[t + off];
        __syncthreads();
    }
    if (t == 0) bsum[blockIdx.x] = red[0];
}

__global__ __launch_bounds__(SCAN_BLK) void k_scan_final(
    const int* __restrict__ counts, const int* __restrict__ bsum,
    int* __restrict__ offsets, int* __restrict__ cursor)
{
    __shared__ int s[SCAN_BLK];
    __shared__ int bs[128];
    const int t = threadIdx.x;
    if (t < 128) bs[t] = (t < SCAN_NB) ? bsum[t] : 0;
    __syncthreads();
    #pragma unroll
    for (int off = 1; off < 128; off <<= 1) {       // inclusive scan of bsum
        int u = 0;
        if (t < 128 && t >= off) u = bs[t - off];
        __syncthreads();
        if (t < 128) bs[t] += u;
        __syncthreads();
    }
    const int i = blockIdx.x * SCAN_BLK + t;
    const int v = (i < N_NODES) ? counts[i] : 0;
    s[t] = v;
    __syncthreads();
    #pragma unroll
    for (int off = 1; off < SCAN_BLK; off <<= 1) {
        const int u = (t >= off) ? s[t - off] : 0;
        __syncthreads();
        s[t] += u;
        __syncthreads();
    }
    const int bpre = (blockIdx.x == 0) ? 0 : bs[blockIdx.x - 1];
    if (i < N_NODES) {
        const int ex = bpre + s[t] - v;
        offsets[i] = ex;
        cursor[i] = ex;
    }
    if (blockIdx.x == SCAN_NB - 1 && t == SCAN_BLK - 1)
        offsets[N_NODES] = bs[SCAN_NB - 1];         // total valid edges
}

// scatter src ids into dst-sorted order (4B per edge; weights computed later)
__global__ void k_scatter(const int* __restrict__ ei, int* __restrict__ cursor,
                          int* __restrict__ ssrc)
{
    const int e = blockIdx.x * 256 + threadIdx.x;
    if (e >= N_EDGES) return;
    const int s = ei[e], d = ei[N_EDGES + e];
    if ((unsigned)d >= N_NODES) return;
    const int pos = atomicAdd(&cursor[d], 1);
    ssrc[pos] = ((unsigned)s < N_NODES) ? s : d;   // match k_hist validity
}

// ---------------------------------------------------------------------------
// Kernel C: gather-aggregate, 8-deep software pipeline (+4-deep drain).
// One wave per dst node; lane l<48 owns feature pair (2l, 2l+1).
// Weights computed inline: asrc gather is L2-resident (800 KB table).
// Output g (normalized + gat_bias) packed bf16.
// ---------------------------------------------------------------------------
__global__ __launch_bounds__(256) void k_aggregate(
    const int* __restrict__ offsets, const int* __restrict__ ssrc,
    const unsigned short* __restrict__ hb, const float* __restrict__ asrc,
    const float* __restrict__ adst, const float* __restrict__ gb,
    unsigned short* __restrict__ gbuf)
{
    const int wid  = (blockIdx.x * 256 + threadIdx.x) >> 6;
    const int lane = threadIdx.x & 63;
    if (wid >= N_NODES) return;
    const int d = wid;
    const int lp = (lane < 48) ? lane : 47;     // lanes 48-63 duplicate lane 47
    const int f0 = lp * 2;                      // features f0, f0+1 (same head)
    const int hd = f0 / HEAD_DIM;

    const int rs = offsets[d], re = offsets[d + 1];
    const int deg = re - rs;
    const int sv = (lane < deg) ? ssrc[rs + lane] : 0;   // coalesced preload
    const float adw = adst[d * HEADS + hd];              // node-constant

    float acc0, acc1, ds;
    {   // self-loop term (overlaps the sv load latency)
        const unsigned int hp = *(const unsigned int*)&hb[(size_t)d * DIM + f0];
        float l0 = asrc[d * HEADS + hd] + adw;
        l0 = (l0 > 0.f) ? l0 : SLOPE * l0;
        const float w = __expf(l0);
        acc0 = w * bf2f((unsigned short)(hp & 0xffffu));
        acc1 = w * bf2f((unsigned short)(hp >> 16));
        ds = w;
    }

#define SRCJ(j) (((j) < 64) ? __shfl(sv, (j)) : ssrc[rs + (j)])
#define ISSUE(hreg, areg, j) do { \
        const int s_ = SRCJ(j); \
        hreg = *(const unsigned int*)&hb[(size_t)s_ * DIM + f0]; \
        areg = asrc[s_ * HEADS + hd]; } while (0)
#define CONSUME(hreg, areg) do { \
        float l_ = (areg) + adw; l_ = (l_ > 0.f) ? l_ : SLOPE * l_; \
        const float w_ = __expf(l_); \
        acc0 += w_ * bf2f((unsigned short)((hreg) & 0xffffu)); \
        acc1 += w_ * bf2f((unsigned short)((hreg) >> 16)); \
        ds += w_; } while (0)

    int j = 0;
    if (deg >= 8) {                             // 8-deep main pipeline
        unsigned p0, p1, p2, p3, p4, p5, p6, p7;
        float    q0, q1, q2, q3, q4, q5, q6, q7;
        ISSUE(p0, q0, 0); ISSUE(p1, q1, 1); ISSUE(p2, q2, 2); ISSUE(p3, q3, 3);
        ISSUE(p4, q4, 4); ISSUE(p5, q5, 5); ISSUE(p6, q6, 6); ISSUE(p7, q7, 7);
        for (; j + 16 <= deg; j += 8) {
            CONSUME(p0, q0); ISSUE(p0, q0, j + 8);
            CONSUME(p1, q1); ISSUE(p1, q1, j + 9);
            CONSUME(p2, q2); ISSUE(p2, q2, j + 10);
            CONSUME(p3, q3); ISSUE(p3, q3, j + 11);
            CONSUME(p4, q4); ISSUE(p4, q4, j + 12);
            CONSUME(p5, q5); ISSUE(p5, q5, j + 13);
            CONSUME(p6, q6); ISSUE(p6, q6, j + 14);
            CONSUME(p7, q7); ISSUE(p7, q7, j + 15);
        }
        CONSUME(p0, q0); CONSUME(p1, q1); CONSUME(p2, q2); CONSUME(p3, q3);
        CONSUME(p4, q4); CONSUME(p5, q5); CONSUME(p6, q6); CONSUME(p7, q7);
        j += 8;
    }
    if (j + 4 <= deg) {                         // 4-deep drain
        unsigned pa, pb_, pc, pd;
        float    qa, qb, qc, qd;
        ISSUE(pa, qa, j); ISSUE(pb_, qb, j + 1); ISSUE(pc, qc, j + 2); ISSUE(pd, qd, j + 3);
        CONSUME(pa, qa); CONSUME(pb_, qb); CONSUME(pc, qc); CONSUME(pd, qd);
        j += 4;
    }
    for (; j < deg; ++j) {                      // <=3 scalar tail
        unsigned hh; float aa;
        ISSUE(hh, aa, j); CONSUME(hh, aa);
    }
#undef SRCJ
#undef ISSUE
#undef CONSUME

    if (lane < 48) {
        const float inv = 1.f / ds;             // ds > 0 (self-loop)
        const float o0 = acc0 * inv + gb[f0];
        const float o1 = acc1 * inv + gb[f0 + 1];
        *(unsigned*)&gbuf[(size_t)d * DIM + f0] = pack2bf(o0, o1);
    }
}

// ---------------------------------------------------------------------------
// Kernel D: proj = g @ PW^T via pre-transposed PWT (row-major [k][f]),
// g staged from bf16, 2-node x 8-feat register tile, + residual + LN.
// ---------------------------------------------------------------------------
__global__ __launch_bounds__(GT) void k_finalize(
    const float* __restrict__ x, const float* __restrict__ PWT,
    const float* __restrict__ pb, const float* __restrict__ lng,
    const float* __restrict__ lnb, const unsigned short* __restrict__ gbuf,
    float* __restrict__ out)
{
    __shared__ float Wl[DIM][DIM];        // PWT tile [k][f] 36.9 KB
    __shared__ float gl[TNODES][XPAD];    // 25.6 KB (g tile, reused as z tile)
    __shared__ float sred[TNODES][6], s2red[TNODES][6];
    __shared__ float mubuf[TNODES], ivbuf[TNODES];
    __shared__ float lngl[DIM], lnbl[DIM];
    const int tid = threadIdx.x;
    for (int i4 = tid; i4 < DIM * (DIM / 4); i4 += GT) {
        const int k = i4 / 24, q = i4 % 24;
        *(float4*)&Wl[k][q * 4] = *(const float4*)&PWT[k * DIM + q * 4];
    }
    if (tid < DIM) { lngl[tid] = lng[tid]; lnbl[tid] = lnb[tid]; }
    const int tf = tid % 12, tn = tid / 12;
    const int f0 = tf * 8, n0 = tn * 2;
    const float4 pba = *(const float4*)&pb[f0];
    const float4 pbb = *(const float4*)&pb[f0 + 4];

    for (int tile = blockIdx.x; tile < NTILES; tile += gridDim.x) {
        const int base = tile * TNODES;
        __syncthreads();
        for (int i8 = tid; i8 < TNODES * 12; i8 += GT) {   // 8 bf16 per iter
            const int n = i8 / 12, q = i8 % 12, gn = base + n;
            float4 lo = make_float4(0.f, 0.f, 0.f, 0.f), hi = lo;
            if (gn < N_NODES) {
                const uint4 gv = *(const uint4*)&gbuf[(size_t)gn * DIM + q * 8];
                lo = make_float4(bf2f((unsigned short)(gv.x & 0xffffu)),
                                 bf2f((unsigned short)(gv.x >> 16)),
                                 bf2f((unsigned short)(gv.y & 0xffffu)),
                                 bf2f((unsigned short)(gv.y >> 16)));
                hi = make_float4(bf2f((unsigned short)(gv.z & 0xffffu)),
                                 bf2f((unsigned short)(gv.z >> 16)),
                                 bf2f((unsigned short)(gv.w & 0xffffu)),
                                 bf2f((unsigned short)(gv.w >> 16)));
            }
            *(float4*)&gl[n][q * 8]     = lo;
            *(float4*)&gl[n][q * 8 + 4] = hi;
        }
        __syncthreads();
        float acc[2][8] = {};
        for (int k = 0; k < DIM; k += 4) {
            float4 gq[2], wa[4], wb[4];
            #pragma unroll
            for (int a = 0; a < 2; ++a) gq[a] = *(const float4*)&gl[n0 + a][k];
            #pragma unroll
            for (int j = 0; j < 4; ++j) {
                wa[j] = *(const float4*)&Wl[k + j][f0];
                wb[j] = *(const float4*)&Wl[k + j][f0 + 4];
            }
            #pragma unroll
            for (int a = 0; a < 2; ++a) {
                const float g0 = gq[a].x, g1 = gq[a].y, g2 = gq[a].z, g3 = gq[a].w;
                acc[a][0] += g0*wa[0].x + g1*wa[1].x + g2*wa[2].x + g3*wa[3].x;
                acc[a][1] += g0*wa[0].y + g1*wa[1].y + g2*wa[2].y + g3*wa[3].y;
                acc[a][2] += g0*wa[0].z + g1*wa[1].z + g2*wa[2].z + g3*wa[3].z;
                acc[a][3] += g0*wa[0].w + g1*wa[1].w + g2*wa[2].w + g3*wa[3].w;
                acc[a][4] += g0*wb[0].x + g1*wb[1].x + g2*wb[2].x + g3*wb[3].x;
                acc[a][5] += g0*wb[0].y + g1*wb[1].y + g2*wb[2].y + g3*wb[3].y;
                acc[a][6] += g0*wb[0].z + g1*wb[1].z + g2*wb[2].z + g3*wb[3].z;
                acc[a][7] += g0*wb[0].w + g1*wb[1].w + g2*wb[2].w + g3*wb[3].w;
            }
        }
        // z = x + pb + proj (registers)
        float4 za[2], zb[2];
        #pragma unroll
        for (int a = 0; a < 2; ++a) {
            const int gn = base + n0 + a;
            float4 xa = make_float4(0.f,0.f,0.f,0.f), xb = xa;
            if (gn < N_NODES) {
                xa = *(const float4*)&x[(size_t)gn * DIM + f0];
                xb = *(const float4*)&x[(size_t)gn * DIM + f0 + 4];
            }
            za[a] = make_float4(acc[a][0]+pba.x+xa.x, acc[a][1]+pba.y+xa.y,
                                acc[a][2]+pba.z+xa.z, acc[a][3]+pba.w+xa.w);
            zb[a] = make_float4(acc[a][4]+pbb.x+xb.x, acc[a][5]+pbb.y+xb.y,
                                acc[a][6]+pbb.z+xb.z, acc[a][7]+pbb.w+xb.w);
        }
        __syncthreads();   // gl (g) reads done -> reuse as z tile
        #pragma unroll
        for (int a = 0; a < 2; ++a) {
            *(float4*)&gl[n0 + a][f0]     = za[a];
            *(float4*)&gl[n0 + a][f0 + 4] = zb[a];
        }
        __syncthreads();
        for (int i = tid; i < TNODES * 6; i += GT) {   // partials: 6/node x 16
            const int n = i / 6, jj = i % 6;
            float s = 0.f, s2 = 0.f;
            #pragma unroll
            for (int c = 0; c < 16; ++c) {
                const float v = gl[n][jj * 16 + c];
                s += v; s2 += v * v;
            }
            sred[n][jj] = s; s2red[n][jj] = s2;
        }
        __syncthreads();
        if (tid < TNODES) {
            float s = 0.f, s2 = 0.f;
            #pragma unroll
            for (int jj = 0; jj < 6; ++jj) { s += sred[tid][jj]; s2 += s2red[tid][jj]; }
            const float mu = s * (1.f / DIM);
            const float var = s2 * (1.f / DIM) - mu * mu;
            mubuf[tid] = mu;
            ivbuf[tid] = rsqrtf(var + LN_EPS);
        }
        __syncthreads();
        for (int i = tid; i < TNODES * 24; i += GT) {
            const int n = i / 24, c = i % 24, gn = base + n;
            if (gn < N_NODES) {
                const float4 v = *(const float4*)&gl[n][c * 4];
                const float mu = mubuf[n], iv = ivbuf[n];
                float4 o;
                o.x = lngl[c*4+0] * (v.x - mu) * iv + lnbl[c*4+0];
                o.y = lngl[c*4+1] * (v.y - mu) * iv + lnbl[c*4+1];
                o.z = lngl[c*4+2] * (v.z - mu) * iv + lnbl[c*4+2];
                o.w = lngl[c*4+3] * (v.w - mu) * iv + lnbl[c*4+3];
                *(float4*)&out[(size_t)gn * DIM + c * 4] = o;
            }
        }
    }
}

// ---------------------------------------------------------------------------
extern "C" void kernel_launch(void* const* d_in, const int* in_sizes, int n_in,
                              void* d_out, int out_size, void* d_ws, size_t ws_size,
                              hipStream_t stream)
{
    const float* x    = (const float*)d_in[0];
    const int*   ei   = (const int*)d_in[1];     // [2, E] int32 (harness-converted)
    const float* W    = (const float*)d_in[2];
    const float* attS = (const float*)d_in[3];
    const float* attD = (const float*)d_in[4];
    const float* gb   = (const float*)d_in[5];
    const float* PW   = (const float*)d_in[6];
    const float* pb   = (const float*)d_in[7];
    const float* lng  = (const float*)d_in[8];
    const float* lnb  = (const float*)d_in[9];
    float* out = (float*)d_out;

    char* ws = (char*)d_ws;
    float* asrc    = (float*)ws;                                  // N*4 (16B-aligned)
    float* adst    = asrc + N_NODES * HEADS;                      // N*4
    unsigned short* hb   = (unsigned short*)(adst + N_NODES * HEADS); // N*96 bf16
    unsigned short* gbuf = hb + (size_t)N_NODES * DIM;            // N*96 bf16
    float* pwt     = (float*)(gbuf + (size_t)N_NODES * DIM);      // 96*96 f32
    int*   counts  = (int*)(pwt + DIM * DIM);                     // N
    int*   offsets = counts + N_NODES;                            // N+1
    int*   cursor  = offsets + N_NODES + 1;                       // N
    int*   bsum    = cursor + N_NODES;                            // SCAN_NB
    int*   ssrc    = bsum + SCAN_NB;                              // E

    k_prep        <<<(N_NODES + 255) / 256, 256, 0, stream>>>(PW, pwt, counts);
    k_hist        <<<(N_EDGES + 255) / 256, 256, 0, stream>>>(ei, counts);
    k_scan_partial<<<SCAN_NB, SCAN_BLK, 0, stream>>>(counts, bsum);
    k_scan_final  <<<SCAN_NB, SCAN_BLK, 0, stream>>>(counts, bsum, offsets, cursor);
    k_scatter     <<<(N_EDGES + 255) / 256, 256, 0, stream>>>(ei, cursor, ssrc);
    k_transform   <<<NTILES, GT, 0, stream>>>(x, W, attS, attD, hb, asrc, adst);
    k_aggregate   <<<(N_NODES * 64 + 255) / 256, 256, 0, stream>>>(offsets, ssrc, hb, asrc, adst, gb, gbuf);
    k_finalize    <<<NTILES, GT, 0, stream>>>(x, pwt, pb, lng, lnb, gbuf, out);
}